// Round 2
// baseline (342.859 us; speedup 1.0000x reference)
//
#include <hip/hip_runtime.h>

#define LOG2E 1.44269504088896340736f

typedef short bf16x8 __attribute__((ext_vector_type(8)));
typedef float f32x4 __attribute__((ext_vector_type(4)));

__device__ inline ushort f2bf(float f) {
    unsigned u = __builtin_bit_cast(unsigned, f);
    unsigned lsb = (u >> 16) & 1u;
    u += 0x7fffu + lsb;
    return (ushort)(u >> 16);
}

// fp32 -> bf16 cast, 8 elems/thread
__global__ void cast_f32_bf16(const float* __restrict__ src, ushort* __restrict__ dst, int n) {
    int i = (blockIdx.x * 256 + threadIdx.x) * 8;
    if (i >= n) return;
    float4 a = *(const float4*)(src + i);
    float4 b = *(const float4*)(src + i + 4);
    union { ushort u[8]; float4 v; } o;
    o.u[0] = f2bf(a.x); o.u[1] = f2bf(a.y); o.u[2] = f2bf(a.z); o.u[3] = f2bf(a.w);
    o.u[4] = f2bf(b.x); o.u[5] = f2bf(b.y); o.u[6] = f2bf(b.z); o.u[7] = f2bf(b.w);
    *(float4*)(dst + i) = o.v;
}

// C = X @ W^T (+bias), X:[M,K] bf16, W:[N,K] bf16, row-major. bias fp32.
// MODE 0: out = acc+bias (bf16)
// MODE 1: out = (acc+bias) * 0.125 * s_in[m,n>>2]   (Q projection, scale+1/sqrt(D) folded)
// MODE 2: s_out[m,n] = sigmoid(acc+bias)*0.1+0.95 (fp32), N must be 256
template<int MODE>
__launch_bounds__(256, 2)
__global__ void gemm_bt(const ushort* __restrict__ X, const ushort* __restrict__ W,
                        const float* __restrict__ bias,
                        ushort* __restrict__ out, float* __restrict__ s_out,
                        const float* __restrict__ s_in,
                        int M, int N, int K)
{
    __shared__ ushort As[128 * 72];
    __shared__ ushort Bs[128 * 72];
    const int tid = threadIdx.x;
    const int m0 = blockIdx.y * 128, n0 = blockIdx.x * 128;
    const int w = tid >> 6, lane = tid & 63;
    const int wm = (w >> 1) * 64, wn = (w & 1) * 64;
    const int l15 = lane & 15, quad = lane >> 4;

    f32x4 acc[4][4];
    for (int i = 0; i < 4; i++) for (int j = 0; j < 4; j++) acc[i][j] = (f32x4){0.f, 0.f, 0.f, 0.f};

    for (int k0 = 0; k0 < K; k0 += 64) {
        __syncthreads();
        for (int it = 0; it < 4; ++it) {
            int l = tid + it * 256;
            int r = l >> 3, c = (l & 7) * 8;
            *(float4*)(&As[r * 72 + c]) = *(const float4*)(&X[(size_t)(m0 + r) * K + k0 + c]);
            *(float4*)(&Bs[r * 72 + c]) = *(const float4*)(&W[(size_t)(n0 + r) * K + k0 + c]);
        }
        __syncthreads();
        for (int kk = 0; kk < 64; kk += 32) {
            bf16x8 a[4], b[4];
            for (int i = 0; i < 4; i++) a[i] = *(const bf16x8*)(&As[(wm + i * 16 + l15) * 72 + kk + quad * 8]);
            for (int j = 0; j < 4; j++) b[j] = *(const bf16x8*)(&Bs[(wn + j * 16 + l15) * 72 + kk + quad * 8]);
            for (int i = 0; i < 4; i++)
                for (int j = 0; j < 4; j++)
                    acc[i][j] = __builtin_amdgcn_mfma_f32_16x16x32_bf16(a[i], b[j], acc[i][j], 0, 0, 0);
        }
    }

    for (int i = 0; i < 4; i++) {
        for (int j = 0; j < 4; j++) {
            int gn = n0 + wn + j * 16 + l15;
            float bv = bias[gn];
            for (int r = 0; r < 4; r++) {
                int gm = m0 + wm + i * 16 + quad * 4 + r;
                float v = acc[i][j][r] + bv;
                if (MODE == 2) {
                    float sg = 1.0f / (1.0f + exp2f(-v * LOG2E));
                    s_out[(size_t)gm * 256 + gn] = sg * 0.1f + 0.95f;
                } else {
                    if (MODE == 1) v *= 0.125f * s_in[(size_t)gm * 256 + (gn >> 2)];
                    out[(size_t)gm * N + gn] = f2bf(v);
                }
            }
        }
    }
}

// Flash attention. Q pre-scaled by s*0.125. Q,K,V: [4096,1024] bf16 (rows=b*2048+s, cols=h*64+d).
// grid: (S/128, B*H), block 256. Wave w owns q-rows w*32..w*32+31 of the 128-row tile.
// out: fp32 [4096,1024].
__launch_bounds__(256, 2)
__global__ void attn_kernel(const ushort* __restrict__ Q, const ushort* __restrict__ K,
                            const ushort* __restrict__ V, float* __restrict__ out)
{
    __shared__ ushort Qs[128 * 72];
    __shared__ ushort Ks[64 * 72];
    __shared__ ushort Vt[64 * 72];   // Vt[d][k]
    __shared__ ushort Ps[128 * 72];  // wave-private 32-row strips

    const int tid = threadIdx.x, w = tid >> 6, lane = tid & 63;
    const int l15 = lane & 15, quad = lane >> 4;
    const int bh = blockIdx.y, b = bh >> 4, h = bh & 15;
    const int q0 = blockIdx.x * 128;
    const size_t rowbase = (size_t)b * 2048;
    const int cbase = h * 64;

    // stage Q tile once (first use is after two __syncthreads in the loop)
    for (int it = 0; it < 4; ++it) {
        int l = tid + it * 256;
        int r = l >> 3, c = (l & 7) * 8;
        *(float4*)(&Qs[r * 72 + c]) = *(const float4*)(&Q[(rowbase + q0 + r) * 1024 + cbase + c]);
    }

    float mstat[2][4], lstat[2][4];
    f32x4 o[2][4];
    for (int mt = 0; mt < 2; mt++)
        for (int r = 0; r < 4; r++) { mstat[mt][r] = -1e30f; lstat[mt][r] = 0.f; }
    for (int mt = 0; mt < 2; mt++)
        for (int nt = 0; nt < 4; nt++) o[mt][nt] = (f32x4){0.f, 0.f, 0.f, 0.f};

    for (int kt = 0; kt < 2048 / 64; ++kt) {
        __syncthreads();  // previous PV done reading Ks/Vt
        for (int it = 0; it < 2; ++it) {
            int l = tid + it * 256;
            int r = l >> 3, c = (l & 7) * 8;
            *(float4*)(&Ks[r * 72 + c]) = *(const float4*)(&K[(rowbase + kt * 64 + r) * 1024 + cbase + c]);
        }
        {
            int k = tid >> 2, d0 = (tid & 3) * 16;
            const ushort* vrow = &V[(rowbase + kt * 64 + k) * 1024 + cbase + d0];
            union { float4 f[2]; ushort u[16]; } uu;
            uu.f[0] = *(const float4*)(vrow);
            uu.f[1] = *(const float4*)(vrow + 8);
            for (int i = 0; i < 16; i++) Vt[(d0 + i) * 72 + k] = uu.u[i];
        }
        __syncthreads();

        // S = Q @ K^T  (16x16 tiles: 2 m-tiles x 4 n-tiles)
        f32x4 sacc[2][4];
        for (int mt = 0; mt < 2; mt++) for (int nt = 0; nt < 4; nt++) sacc[mt][nt] = (f32x4){0.f, 0.f, 0.f, 0.f};
        for (int kk = 0; kk < 64; kk += 32) {
            bf16x8 a[2], bfr[4];
            for (int mt = 0; mt < 2; mt++) a[mt] = *(const bf16x8*)(&Qs[(w * 32 + mt * 16 + l15) * 72 + kk + quad * 8]);
            for (int nt = 0; nt < 4; nt++) bfr[nt] = *(const bf16x8*)(&Ks[(nt * 16 + l15) * 72 + kk + quad * 8]);
            for (int mt = 0; mt < 2; mt++)
                for (int nt = 0; nt < 4; nt++)
                    sacc[mt][nt] = __builtin_amdgcn_mfma_f32_16x16x32_bf16(a[mt], bfr[nt], sacc[mt][nt], 0, 0, 0);
        }

        // online softmax per q-row (row = quad*4 + r within each 16-row m-tile)
        for (int mt = 0; mt < 2; mt++) {
            for (int r = 0; r < 4; r++) {
                float mx = sacc[mt][0][r];
                mx = fmaxf(mx, sacc[mt][1][r]);
                mx = fmaxf(mx, sacc[mt][2][r]);
                mx = fmaxf(mx, sacc[mt][3][r]);
                for (int off = 1; off < 16; off <<= 1) mx = fmaxf(mx, __shfl_xor(mx, off));
                float mold = mstat[mt][r];
                float mnew = fmaxf(mold, mx);
                float alpha = exp2f((mold - mnew) * LOG2E);
                float sum = 0.f;
                for (int nt = 0; nt < 4; nt++) {
                    float p = exp2f((sacc[mt][nt][r] - mnew) * LOG2E);
                    sacc[mt][nt][r] = p;
                    sum += p;
                }
                for (int off = 1; off < 16; off <<= 1) sum += __shfl_xor(sum, off);
                lstat[mt][r] = lstat[mt][r] * alpha + sum;
                mstat[mt][r] = mnew;
                for (int nt = 0; nt < 4; nt++) o[mt][nt][r] *= alpha;
            }
            for (int nt = 0; nt < 4; nt++)
                for (int r = 0; r < 4; r++)
                    Ps[(w * 32 + mt * 16 + quad * 4 + r) * 72 + nt * 16 + l15] = f2bf(sacc[mt][nt][r]);
        }
        __syncthreads();  // Ps visibility (wave-private, but keeps ordering simple)

        // O += P @ V  (A from Ps rows, B from Vt rows)
        for (int kk = 0; kk < 64; kk += 32) {
            bf16x8 a[2], bfr[4];
            for (int mt = 0; mt < 2; mt++) a[mt] = *(const bf16x8*)(&Ps[(w * 32 + mt * 16 + l15) * 72 + kk + quad * 8]);
            for (int nt = 0; nt < 4; nt++) bfr[nt] = *(const bf16x8*)(&Vt[(nt * 16 + l15) * 72 + kk + quad * 8]);
            for (int mt = 0; mt < 2; mt++)
                for (int nt = 0; nt < 4; nt++)
                    o[mt][nt] = __builtin_amdgcn_mfma_f32_16x16x32_bf16(a[mt], bfr[nt], o[mt][nt], 0, 0, 0);
        }
    }

    // epilogue: O / l, store fp32
    for (int mt = 0; mt < 2; mt++) {
        for (int r = 0; r < 4; r++) {
            float inv = 1.0f / lstat[mt][r];
            int q = q0 + w * 32 + mt * 16 + quad * 4 + r;
            size_t base = (rowbase + q) * 1024 + cbase;
            for (int nt = 0; nt < 4; nt++) {
                out[base + nt * 16 + l15] = o[mt][nt][r] * inv;
            }
        }
    }
}

extern "C" void kernel_launch(void* const* d_in, const int* in_sizes, int n_in,
                              void* d_out, int out_size, void* d_ws, size_t ws_size,
                              hipStream_t stream) {
    const float* hs = (const float*)d_in[0];
    const float* Wq = (const float*)d_in[1];
    const float* bq = (const float*)d_in[2];
    const float* Wk = (const float*)d_in[3];
    const float* bk = (const float*)d_in[4];
    const float* Wv = (const float*)d_in[5];
    const float* bv = (const float*)d_in[6];
    const float* Ws = (const float*)d_in[7];
    const float* bs = (const float*)d_in[8];
    float* outp = (float*)d_out;

    char* ws = (char*)d_ws;
    ushort* Qb    = (ushort*)(ws);                 //  8 MB
    ushort* Kb    = (ushort*)(ws + 8388608);       //  8 MB
    ushort* Vb    = (ushort*)(ws + 16777216);      //  8 MB
    float*  sb    = (float* )(ws + 25165824);      //  4 MB
    ushort* hs_bf = (ushort*)(ws + 29360128);      //  8 MB
    ushort* Wq_bf = (ushort*)(ws + 37748736);      //  2 MB
    ushort* Wk_bf = (ushort*)(ws + 39845888);      //  2 MB
    ushort* Wv_bf = (ushort*)(ws + 41943040);      //  2 MB
    ushort* Ws_bf = (ushort*)(ws + 44040192);      // 0.5 MB
    // total 44,564,480 bytes

    dim3 blk(256);
    cast_f32_bf16<<<dim3(4194304 / 2048), blk, 0, stream>>>(hs, hs_bf, 4194304);
    cast_f32_bf16<<<dim3(1048576 / 2048), blk, 0, stream>>>(Wq, Wq_bf, 1048576);
    cast_f32_bf16<<<dim3(1048576 / 2048), blk, 0, stream>>>(Wk, Wk_bf, 1048576);
    cast_f32_bf16<<<dim3(1048576 / 2048), blk, 0, stream>>>(Wv, Wv_bf, 1048576);
    cast_f32_bf16<<<dim3( 262144 / 2048), blk, 0, stream>>>(Ws, Ws_bf, 262144);

    // s-projection first (Q epilogue consumes it)
    gemm_bt<2><<<dim3(2, 32), blk, 0, stream>>>(hs_bf, Ws_bf, bs, nullptr, sb, nullptr, 4096, 256, 1024);
    gemm_bt<1><<<dim3(8, 32), blk, 0, stream>>>(hs_bf, Wq_bf, bq, Qb, nullptr, sb, 4096, 1024, 1024);
    gemm_bt<0><<<dim3(8, 32), blk, 0, stream>>>(hs_bf, Wk_bf, bk, Kb, nullptr, nullptr, 4096, 1024, 1024);
    gemm_bt<0><<<dim3(8, 32), blk, 0, stream>>>(hs_bf, Wv_bf, bv, Vb, nullptr, nullptr, 4096, 1024, 1024);
    attn_kernel<<<dim3(16, 32), blk, 0, stream>>>(Qb, Kb, Vb, outp);
}